// Round 1
// baseline (129.004 us; speedup 1.0000x reference)
//
#include <hip/hip_runtime.h>

typedef __bf16 bf16;
typedef __attribute__((ext_vector_type(8))) __bf16 bf16x8;
typedef __attribute__((ext_vector_type(4))) __bf16 bf16x4;
typedef __attribute__((ext_vector_type(4))) float floatx4;

#define MFMA16(a, b, c) __builtin_amdgcn_mfma_f32_16x16x32_bf16((a), (b), (c), 0, 0, 0)

__device__ __forceinline__ float fast_exp2(float xv) {
#if __has_builtin(__builtin_amdgcn_exp2f)
  return __builtin_amdgcn_exp2f(xv);
#else
  return exp2f(xv);
#endif
}

// ---------------- attention kernel ----------------
// grid = 512 (b=128 x h=4), block = 256 (4 waves; wave w owns rows 64w..64w+63)
// S[i][j] = SCALE*cq[i]*ck[j]*dot(A_i,A_j); P=exp(S); out = P*(cv.*A)/rowsum(P)
// smem (bytes):
//   Abf [256][72] bf16 @0      (36864)  A rows, pad 72 for bank-friendly b128
//   Pst 4x[64][40] bf16 @36864 (20480)  per-wave P strip (union: scT/bsT f32 staging)
//   Vt  [64][40] bf16  @57344  (5120)   (cv.*A)^T for current j-tile
//   cqA [256] f32 @62464; ckA [256] f32 @63488; cvA [256] bf16 @64512
// total 65024 B -> 2 blocks/CU
__global__ __launch_bounds__(256) void attn_kernel(
    const float* __restrict__ x,
    const float* __restrict__ bn_gamma, const float* __restrict__ bn_beta,
    const float* __restrict__ bn_mean, const float* __restrict__ bn_var,
    const float* __restrict__ w_qkv,
    float* __restrict__ out)
{
  __shared__ __align__(16) char smem[65024];
  bf16 (*Abf)[72] = (bf16(*)[72])smem;
  bf16* PstBase   = (bf16*)(smem + 36864);
  bf16 (*Vt)[40]  = (bf16(*)[40])(smem + 57344);
  float* cqA = (float*)(smem + 62464);
  float* ckA = (float*)(smem + 63488);
  bf16*  cvA = (bf16*) (smem + 64512);
  float* scT = (float*)(smem + 36864);   // staging-phase union with Pst
  float* bsT = scT + 256;

  const int t  = threadIdx.x;
  const int bb = blockIdx.x >> 2;
  const int h  = blockIdx.x & 3;

  // per-token BN affine + qkv scalar columns
  {
    float inv = rsqrtf(bn_var[t] + 1e-5f);
    float sc  = bn_gamma[t] * inv;
    scT[t] = sc;
    bsT[t] = bn_beta[t] - bn_mean[t] * sc;
    cqA[t] = w_qkv[t*6+0] * (0.125f * 1.44269504088896340736f); // fold SCALE*log2(e)
    ckA[t] = w_qkv[t*6+2];
    cvA[t] = (bf16)w_qkv[t*6+4];
  }
  __syncthreads();

  // stage A = relu(BN(x))[:, h*64 .. h*64+63] as bf16 rows
  {
    const float* xb = x + ((size_t)bb * 256) * 256 + h * 64;
    const int rsub = t >> 4, ch = t & 15;
#pragma unroll
    for (int it = 0; it < 16; ++it) {
      int n = it*16 + rsub;
      float4 v = *(const float4*)(xb + (size_t)n*256 + ch*4);
      float sc = scT[n], bs = bsT[n];
      bf16x4 bv;
      bv.x = (bf16)fmaxf(fmaf(v.x, sc, bs), 0.f);
      bv.y = (bf16)fmaxf(fmaf(v.y, sc, bs), 0.f);
      bv.z = (bf16)fmaxf(fmaf(v.z, sc, bs), 0.f);
      bv.w = (bf16)fmaxf(fmaf(v.w, sc, bs), 0.f);
      *(bf16x4*)&Abf[n][ch*4] = bv;
    }
  }

  const int lane = t & 63;
  const int wid  = t >> 6;
  const int quad = lane >> 4;
  const int col  = lane & 15;
  const int R    = wid * 64;
  bf16 (*Pst)[40] = (bf16(*)[40])(PstBase + wid * (64*40));

  floatx4 oacc[4][4];
  float lacc[4][4];
  float cqr[4][4];
#pragma unroll
  for (int it = 0; it < 4; ++it)
#pragma unroll
    for (int et = 0; et < 4; ++et)
      oacc[it][et] = (floatx4){0.f,0.f,0.f,0.f};
#pragma unroll
  for (int it = 0; it < 4; ++it)
#pragma unroll
    for (int r = 0; r < 4; ++r) {
      lacc[it][r] = 0.f;
      cqr[it][r]  = cqA[R + it*16 + quad*4 + r];
    }

  for (int jt = 0; jt < 8; ++jt) {
    const int j0 = jt * 32;
    __syncthreads();  // Abf ready (jt=0) / prev Vt fully consumed (jt>0)

    // build Vt[e][jl] = cv[j0+jl] * A[j0+jl][e]  (cooperative transpose)
#pragma unroll
    for (int qq = 0; qq < 8; ++qq) {
      int q = qq*256 + t;
      int e = q >> 5, jl = q & 31;
      Vt[e][jl] = (bf16)((float)Abf[j0+jl][e] * (float)cvA[j0+jl]);
    }

    // S = A * A^T tile (rows R..R+63 x cols j0..j0+31), exp, stage P (wave-private)
    bf16x8 bq00 = *(const bf16x8*)&Abf[j0 + col][quad*8];
    bf16x8 bq01 = *(const bf16x8*)&Abf[j0 + col][32 + quad*8];
    bf16x8 bq10 = *(const bf16x8*)&Abf[j0 + 16 + col][quad*8];
    bf16x8 bq11 = *(const bf16x8*)&Abf[j0 + 16 + col][32 + quad*8];
    float ck0 = ckA[j0 + col];
    float ck1 = ckA[j0 + 16 + col];
#pragma unroll
    for (int it = 0; it < 4; ++it) {
      const bf16* arow = &Abf[R + it*16 + col][0];
      bf16x8 a0 = *(const bf16x8*)(arow + quad*8);
      bf16x8 a1 = *(const bf16x8*)(arow + 32 + quad*8);
      floatx4 s0 = (floatx4){0.f,0.f,0.f,0.f};
      floatx4 s1 = (floatx4){0.f,0.f,0.f,0.f};
      s0 = MFMA16(a0, bq00, s0);
      s0 = MFMA16(a1, bq01, s0);
      s1 = MFMA16(a0, bq10, s1);
      s1 = MFMA16(a1, bq11, s1);
#pragma unroll
      for (int r = 0; r < 4; ++r) {
        float p0 = fast_exp2(fminf(cqr[it][r] * ck0 * s0[r], 80.f));
        float p1 = fast_exp2(fminf(cqr[it][r] * ck1 * s1[r], 80.f));
        lacc[it][r] += p0 + p1;
        Pst[it*16 + quad*4 + r][col]      = (bf16)p0;
        Pst[it*16 + quad*4 + r][16 + col] = (bf16)p1;
      }
    }
    __syncthreads();  // Vt visible to all; barrier waitcnt also orders Pst w->r

    // O += P * V  (K = 32)
    bf16x8 vb0 = *(const bf16x8*)&Vt[     col][quad*8];
    bf16x8 vb1 = *(const bf16x8*)&Vt[16 + col][quad*8];
    bf16x8 vb2 = *(const bf16x8*)&Vt[32 + col][quad*8];
    bf16x8 vb3 = *(const bf16x8*)&Vt[48 + col][quad*8];
#pragma unroll
    for (int it = 0; it < 4; ++it) {
      bf16x8 pa = *(const bf16x8*)&Pst[it*16 + col][quad*8];
      oacc[it][0] = MFMA16(pa, vb0, oacc[it][0]);
      oacc[it][1] = MFMA16(pa, vb1, oacc[it][1]);
      oacc[it][2] = MFMA16(pa, vb2, oacc[it][2]);
      oacc[it][3] = MFMA16(pa, vb3, oacc[it][3]);
    }
  }

  // rowsum(P) held distributed: reduce across the 16 lanes of each quad
#pragma unroll
  for (int it = 0; it < 4; ++it)
#pragma unroll
    for (int r = 0; r < 4; ++r) {
      float v = lacc[it][r];
      v += __shfl_xor(v, 1, 64);
      v += __shfl_xor(v, 2, 64);
      v += __shfl_xor(v, 4, 64);
      v += __shfl_xor(v, 8, 64);
      lacc[it][r] = 0.5f / v;   // fold the pair-average 0.5 into 1/l
    }

  // out[b][n][h*32+u] = 0.5*(O[n][2u]+O[n][2u+1])/l[n]
  float* outp = out + ((size_t)bb * 256) * 256 + h * 32;
#pragma unroll
  for (int it = 0; it < 4; ++it)
#pragma unroll
    for (int et = 0; et < 4; ++et)
#pragma unroll
      for (int r = 0; r < 4; ++r) {
        float v  = oacc[it][et][r];
        float v2 = v + __shfl_xor(v, 1, 64);
        if (!(lane & 1)) {
          int n = R + it*16 + quad*4 + r;
          int d = et*8 + (col >> 1);
          outp[(size_t)n*256 + d] = v2 * lacc[it][r];
        }
      }
}

// ---------------- conv (heads 4..7 + depthwise) kernel ----------------
// grid = 4096 (b=128 x 32 c-groups of 8), block = 256.
// output row c needs patch xb[b, 4*(c&63)..+3, (c>>6)*64..+63]; taps p+-1 (q), p+-16 (k)
__global__ __launch_bounds__(256) void conv_kernel(
    const float* __restrict__ x,
    const float* __restrict__ bn_gamma, const float* __restrict__ bn_beta,
    const float* __restrict__ bn_mean, const float* __restrict__ bn_var,
    const float* __restrict__ w_qkv, const float* __restrict__ w_qs,
    const float* __restrict__ w_ks,
    float* __restrict__ out)
{
  __shared__ float X[32][68];
  __shared__ float scA[32], bsA[32], wq1[32], wk1[32], wv1[32];
  __shared__ float qs[8][3], ks[8][3];

  const int t     = threadIdx.x;
  const int bb    = blockIdx.x >> 5;
  const int cg    = blockIdx.x & 31;
  const int cbase = cg * 8;
  const int h2    = cbase >> 6;
  const int N0    = (cbase & 63) * 4;

  if (t < 32) {
    int n = N0 + t;
    float inv = rsqrtf(bn_var[n] + 1e-5f);
    float s = bn_gamma[n] * inv;
    scA[t] = s;
    bsA[t] = bn_beta[n] - bn_mean[n] * s;
    wq1[t] = w_qkv[n*6+1];
    wk1[t] = w_qkv[n*6+3];
    wv1[t] = w_qkv[n*6+5];
  } else if (t < 56) {
    int i = t - 32; int cc = i/3, kk = i - cc*3;
    qs[cc][kk] = w_qs[(cbase+cc)*3 + kk];
  } else if (t < 80) {
    int i = t - 56; int cc = i/3, kk = i - cc*3;
    ks[cc][kk] = w_ks[(cbase+cc)*3 + kk];
  }
  __syncthreads();

  {
    const float* src = x + ((size_t)(bb*256 + N0)) * 256 + h2*64;
#pragma unroll
    for (int ii = 0; ii < 2; ++ii) {
      int idx = t + ii*256;          // 512 float4 chunks: 32 rows x 16 chunks
      int row = idx >> 4, ch = idx & 15;
      float4 v = *(const float4*)(src + (size_t)row*256 + ch*4);
      float s = scA[row], b2 = bsA[row];
      X[row][ch*4+0] = fmaxf(fmaf(v.x, s, b2), 0.f);
      X[row][ch*4+1] = fmaxf(fmaf(v.y, s, b2), 0.f);
      X[row][ch*4+2] = fmaxf(fmaf(v.z, s, b2), 0.f);
      X[row][ch*4+3] = fmaxf(fmaf(v.w, s, b2), 0.f);
    }
  }
  __syncthreads();

  const int cc  = t >> 5;
  const int l32 = t & 31;
  float res[4];
#pragma unroll
  for (int k = 0; k < 4; ++k) {
    int u = l32*4 + k;
    float acc = 0.f;
#pragma unroll
    for (int pp = 0; pp < 2; ++pp) {
      int p  = 2*u + pp;
      int ww = p & 15;
      int lr = cc*4 + (p >> 6);
      int e  = p & 63;
      float fc = X[lr][e];
      float qv = qs[cc][1] * fc;
      if (ww > 0)  qv = fmaf(qs[cc][0], X[lr][e-1], qv);
      if (ww < 15) qv = fmaf(qs[cc][2], X[lr][e+1], qv);
      float val = fmaf(qv, wq1[lr], fc * wv1[lr]);
      float kv = ks[cc][1] * fc * wk1[lr];
      if (p >= 16) {
        int pm = p - 16; int lm = cc*4 + (pm >> 6);
        kv = fmaf(ks[cc][0] * wk1[lm], X[lm][pm & 63], kv);
      }
      if (p < 240) {
        int pq = p + 16; int lp = cc*4 + (pq >> 6);
        kv = fmaf(ks[cc][2] * wk1[lp], X[lp][pq & 63], kv);
      }
      acc += val + kv;
    }
    res[k] = 0.5f * acc;
  }
  float4 o4; o4.x = res[0]; o4.y = res[1]; o4.z = res[2]; o4.w = res[3];
  *(float4*)(out + ((size_t)(bb*256 + cbase + cc)) * 256 + 128 + l32*4) = o4;
}

extern "C" void kernel_launch(void* const* d_in, const int* in_sizes, int n_in,
                              void* d_out, int out_size, void* d_ws, size_t ws_size,
                              hipStream_t stream) {
  (void)in_sizes; (void)n_in; (void)out_size; (void)d_ws; (void)ws_size;
  const float* x    = (const float*)d_in[0];
  const float* g    = (const float*)d_in[1];
  const float* be   = (const float*)d_in[2];
  const float* mn   = (const float*)d_in[3];
  const float* vr   = (const float*)d_in[4];
  const float* wqkv = (const float*)d_in[5];
  const float* wqs  = (const float*)d_in[6];
  const float* wks  = (const float*)d_in[7];
  float* out = (float*)d_out;

  attn_kernel<<<dim3(512), dim3(256), 0, stream>>>(x, g, be, mn, vr, wqkv, out);
  conv_kernel<<<dim3(4096), dim3(256), 0, stream>>>(x, g, be, mn, vr, wqkv, wqs, wks, out);
}

// Round 2
// 113.822 us; speedup vs baseline: 1.1334x; 1.1334x over previous
//
#include <hip/hip_runtime.h>

typedef __bf16 bf16;
typedef __attribute__((ext_vector_type(8))) __bf16 bf16x8;
typedef __attribute__((ext_vector_type(4))) __bf16 bf16x4;
typedef __attribute__((ext_vector_type(2))) __bf16 bf16x2;
typedef __attribute__((ext_vector_type(4))) float floatx4;

#define MFMA16(a,b,c) __builtin_amdgcn_mfma_f32_16x16x32_bf16((a),(b),(c),0,0,0)

__device__ __forceinline__ float fast_exp2(float xv) {
#if __has_builtin(__builtin_amdgcn_exp2f)
  return __builtin_amdgcn_exp2f(xv);
#else
  return exp2f(xv);
#endif
}

__device__ __forceinline__ void ld8f(const bf16* p, float* dst) {
  bf16x8 v = *(const bf16x8*)p;
#pragma unroll
  for (int i = 0; i < 8; ++i) dst[i] = (float)v[i];
}

// Fused attention (heads 0-3) + depthwise-conv residual (heads 4-7).
// grid = 512 (b=128 x slice h=0..3), block = 512 (8 waves; wave w owns i-rows 32w..32w+31).
// S[i][j] = cq[i]*ck[j]*G[i][j], G = A*A^T symmetric. S-tiles computed with swapped
// operands (A-op = j-rows, B-op = i-rows) so each lane's C-frag holds ONE row i=c of P
// -> C->A-operand transform is 8 bpermute + 4 cndmask per it (no LDS roundtrip, no barrier).
// smem: Abf[256][72] bf16 @0 (36864) | Vt[2][64][40] bf16 @36864 (10240, unions:
//       scT/bsT @init, Lsh @epilogue) | ckA f32 @47104 | cvA f32 @48128 | total 49152 -> 2 blk/CU (16 waves)
__global__ __launch_bounds__(512, 4) void fused_kernel(
    const float* __restrict__ x,
    const float* __restrict__ bn_gamma, const float* __restrict__ bn_beta,
    const float* __restrict__ bn_mean, const float* __restrict__ bn_var,
    const float* __restrict__ w_qkv, const float* __restrict__ w_qs,
    const float* __restrict__ w_ks,
    float* __restrict__ out)
{
  __shared__ __align__(16) char smem[49152];
  bf16 (*Abf)[72]    = (bf16(*)[72])smem;
  bf16 (*Vt)[64][40] = (bf16(*)[64][40])(smem + 36864);
  float* ckA = (float*)(smem + 47104);
  float* cvA = (float*)(smem + 48128);
  float* scT = (float*)(smem + 36864);          // init-phase union with Vt
  float* bsT = (float*)(smem + 36864 + 1024);
  float* Lsh = (float*)(smem + 36864);          // epilogue union with Vt[0]

  const int t  = threadIdx.x;
  const int bb = blockIdx.x >> 2;
  const int h  = blockIdx.x & 3;

  if (t < 256) {
    float inv = rsqrtf(bn_var[t] + 1e-5f);
    float sc  = bn_gamma[t] * inv;
    scT[t] = sc;
    bsT[t] = bn_beta[t] - bn_mean[t] * sc;
    ckA[t] = w_qkv[t*6+2];
    cvA[t] = w_qkv[t*6+4];
  }
  __syncthreads();

  // stage A = relu(BN(x))[:, h*64 .. h*64+63] as bf16
  const float* xb = x + (size_t)bb * 65536 + h * 64;
  {
    const int rsub = t >> 4, ch = t & 15;
#pragma unroll
    for (int i2 = 0; i2 < 8; ++i2) {
      int n = i2*32 + rsub;
      float4 v = *(const float4*)(xb + (size_t)n*256 + ch*4);
      float sc = scT[n], bs = bsT[n];
      bf16x4 bv;
      bv.x = (bf16)fmaxf(fmaf(v.x, sc, bs), 0.f);
      bv.y = (bf16)fmaxf(fmaf(v.y, sc, bs), 0.f);
      bv.z = (bf16)fmaxf(fmaf(v.z, sc, bs), 0.f);
      bv.w = (bf16)fmaxf(fmaf(v.w, sc, bs), 0.f);
      *(bf16x4*)&Abf[n][ch*4] = bv;
    }
  }
  __syncthreads();   // Abf complete; scT/bsT dead -> Vt region reusable

  // build Vt[0] (transpose of A rows 0..31); V scaling cv is folded into P
  {
    int j = t & 31, g = t >> 5;
    bf16x4 v = *(const bf16x4*)&Abf[j][g*4];
    Vt[0][g*4+0][j] = v.x; Vt[0][g*4+1][j] = v.y;
    Vt[0][g*4+2][j] = v.z; Vt[0][g*4+3][j] = v.w;
  }

  const int lane = t & 63;
  const int wid  = t >> 6;
  const int q    = lane >> 4;
  const int c    = lane & 15;
  const int R    = wid * 32;
  const bool hi  = (q >= 2);
  const int qa   = q & 1;
  const int srcA = ((qa*2)*16 + c) * 4;     // bpermute byte index, dwords 0,1
  const int srcB = ((qa*2+1)*16 + c) * 4;   // dwords 2,3

  float cqv[2];
  cqv[0] = w_qkv[(R + c)*6]      * 0.18033688f;  // SCALE * log2(e) folded
  cqv[1] = w_qkv[(R + 16 + c)*6] * 0.18033688f;

  floatx4 oacc[2][4];
  float lacc[2] = {0.f, 0.f};
#pragma unroll
  for (int it = 0; it < 2; ++it)
#pragma unroll
    for (int et = 0; et < 4; ++et)
      oacc[it][et] = (floatx4){0.f,0.f,0.f,0.f};

  for (int jt = 0; jt < 8; ++jt) {
    const int j0  = jt * 32;
    const int cur = jt & 1;
    __syncthreads();   // Vt[cur] ready; prev iter's Vt reads done

    if (jt < 7) {      // build next Vt buffer
      int j = t & 31, g = t >> 5;
      bf16x4 v = *(const bf16x4*)&Abf[j0 + 32 + j][g*4];
      Vt[cur^1][g*4+0][j] = v.x; Vt[cur^1][g*4+1][j] = v.y;
      Vt[cur^1][g*4+2][j] = v.z; Vt[cur^1][g*4+3][j] = v.w;
    }

    // A-operand = j-rows (swapped-operand trick)
    bf16x8 aj00 = *(const bf16x8*)&Abf[j0 + c][8*q];
    bf16x8 aj01 = *(const bf16x8*)&Abf[j0 + c][32 + 8*q];
    bf16x8 aj10 = *(const bf16x8*)&Abf[j0 + 16 + c][8*q];
    bf16x8 aj11 = *(const bf16x8*)&Abf[j0 + 16 + c][32 + 8*q];
    floatx4 ckv0 = *(const floatx4*)&ckA[j0 + 4*q];
    floatx4 ckv1 = *(const floatx4*)&ckA[j0 + 16 + 4*q];
    floatx4 cvv0 = *(const floatx4*)&cvA[j0 + 4*q];
    floatx4 cvv1 = *(const floatx4*)&cvA[j0 + 16 + 4*q];

    unsigned int paU[2][4];
#pragma unroll
    for (int it = 0; it < 2; ++it) {
      const bf16* bp = &Abf[R + 16*it + c][0];
      bf16x8 bi0 = *(const bf16x8*)(bp + 8*q);
      bf16x8 bi1 = *(const bf16x8*)(bp + 32 + 8*q);
      floatx4 s0 = (floatx4){0.f,0.f,0.f,0.f};
      floatx4 s1 = (floatx4){0.f,0.f,0.f,0.f};
      s0 = MFMA16(aj00, bi0, s0); s0 = MFMA16(aj01, bi1, s0);
      s1 = MFMA16(aj10, bi0, s1); s1 = MFMA16(aj11, bi1, s1);
      // lane (q,c) now holds G[j-local=4q+r][i=R+16it+c] = G[i][j] by symmetry
      float p0[4], p1[4];
#pragma unroll
      for (int r = 0; r < 4; ++r) {
        float e0v = fast_exp2(fminf(cqv[it]*ckv0[r]*s0[r], 80.f));
        float e1v = fast_exp2(fminf(cqv[it]*ckv1[r]*s1[r], 80.f));
        lacc[it] += e0v + e1v;
        p0[r] = e0v * cvv0[r];   // fold V's cv scale into P
        p1[r] = e1v * cvv1[r];
      }
      union { bf16x2 hh; unsigned int u; } pk00, pk01, pk10, pk11;
      pk00.hh = (bf16x2){(bf16)p0[0], (bf16)p0[1]};
      pk01.hh = (bf16x2){(bf16)p0[2], (bf16)p0[3]};
      pk10.hh = (bf16x2){(bf16)p1[0], (bf16)p1[1]};
      pk11.hh = (bf16x2){(bf16)p1[2], (bf16)p1[3]};
      // quad-regroup: target dword k = {P[c][j0+8q+2k], P[c][j0+8q+2k+1]}
      unsigned int a0, a1;
      a0 = (unsigned)__builtin_amdgcn_ds_bpermute(srcA, (int)pk00.u);
      a1 = (unsigned)__builtin_amdgcn_ds_bpermute(srcA, (int)pk10.u);
      paU[it][0] = hi ? a1 : a0;
      a0 = (unsigned)__builtin_amdgcn_ds_bpermute(srcA, (int)pk01.u);
      a1 = (unsigned)__builtin_amdgcn_ds_bpermute(srcA, (int)pk11.u);
      paU[it][1] = hi ? a1 : a0;
      a0 = (unsigned)__builtin_amdgcn_ds_bpermute(srcB, (int)pk00.u);
      a1 = (unsigned)__builtin_amdgcn_ds_bpermute(srcB, (int)pk10.u);
      paU[it][2] = hi ? a1 : a0;
      a0 = (unsigned)__builtin_amdgcn_ds_bpermute(srcB, (int)pk01.u);
      a1 = (unsigned)__builtin_amdgcn_ds_bpermute(srcB, (int)pk11.u);
      paU[it][3] = hi ? a1 : a0;
    }

    union PAu { unsigned int u[4]; bf16x8 v; };
    PAu pa0, pa1;
#pragma unroll
    for (int k = 0; k < 4; ++k) { pa0.u[k] = paU[0][k]; pa1.u[k] = paU[1][k]; }

#pragma unroll
    for (int et = 0; et < 4; ++et) {
      bf16x8 vb = *(const bf16x8*)&Vt[cur][16*et + c][8*q];
      oacc[0][et] = MFMA16(pa0.v, vb, oacc[0][et]);
      oacc[1][et] = MFMA16(pa1.v, vb, oacc[1][et]);
    }
  }

  __syncthreads();   // all Vt reads done -> Lsh may reuse Vt[0] space

  // rowsum reduce across quads; broadcast via wave-private LDS strip
#pragma unroll
  for (int it = 0; it < 2; ++it) {
    float v = lacc[it];
    v += __shfl_xor(v, 16, 64);
    v += __shfl_xor(v, 32, 64);
    lacc[it] = v;
  }
  if (q == 0) {
    Lsh[R + c]      = lacc[0];
    Lsh[R + 16 + c] = lacc[1];
  }
  floatx4 l40 = *(const floatx4*)&Lsh[R + 4*q];        // in-wave LDS, ordered by lgkmcnt
  floatx4 l41 = *(const floatx4*)&Lsh[R + 16 + 4*q];

  float* outA = out + ((size_t)bb*256)*256 + h*32;
#pragma unroll
  for (int it = 0; it < 2; ++it) {
    floatx4 l4 = it ? l41 : l40;
#pragma unroll
    for (int r = 0; r < 4; ++r) {
      float linv = 0.5f / l4[r];       // fold pair-average 0.5
      int n = R + 16*it + 4*q + r;
#pragma unroll
      for (int et = 0; et < 4; ++et) {
        float v = oacc[it][et][r];
        float v2 = v + __shfl_xor(v, 1, 64);
        if (!(lane & 1))
          outA[(size_t)n*256 + 8*et + (c>>1)] = v2 * linv;
      }
    }
  }

  // ---------------- conv phase (heads 4..7), reads Abf ----------------
  // thread: C-row ci, quarter qq, half uh; p = 64*qq + 32*uh + k, k=0..31
  {
    const int ci = t >> 3, sub = t & 7, qq = sub >> 1, uh = sub & 1;
    const int C  = h*64 + ci;
    const int a  = 4*ci + qq;
    const int e0 = 32*uh;

    float qs0 = w_qs[C*3+0], qs1 = w_qs[C*3+1], qs2 = w_qs[C*3+2];
    float ks0 = w_ks[C*3+0], ks1 = w_ks[C*3+1], ks2 = w_ks[C*3+2];
    float wq1a = w_qkv[a*6+1], wk1a = w_qkv[a*6+3], wv1a = w_qkv[a*6+5];
    float wcf = fmaf(ks1, wk1a, wv1a);

    // minus-tap (k<16): row = uh? a : a-1; valid iff uh||qq>0
    float wmx = 0.f;
    if (uh) wmx = ks0 * wk1a;
    else if (qq > 0) wmx = ks0 * w_qkv[(a-1)*6+3];
    float wmh = ks0 * wk1a;                    // minus-tap (k>=16), row a
    float wpl = ks2 * wk1a;                    // plus-tap (k<16), row a
    float wpx = 0.f;                           // plus-tap (k>=16)
    if (!uh) wpx = ks2 * wk1a;
    else if (qq < 3) wpx = ks2 * w_qkv[(a+1)*6+3];

    float Xc[32], Xl[16], Xr[16];
#pragma unroll
    for (int m = 0; m < 4; ++m) ld8f(&Abf[a][e0 + 8*m], &Xc[8*m]);
    if (uh) {
      ld8f(&Abf[a][16], &Xl[0]); ld8f(&Abf[a][24], &Xl[8]);
    } else if (qq > 0) {
      ld8f(&Abf[a-1][48], &Xl[0]); ld8f(&Abf[a-1][56], &Xl[8]);
    } else {
#pragma unroll
      for (int i = 0; i < 16; ++i) Xl[i] = 0.f;
    }
    if (!uh) {
      ld8f(&Abf[a][32], &Xr[0]); ld8f(&Abf[a][40], &Xr[8]);
    } else if (qq < 3) {
      ld8f(&Abf[a+1][0], &Xr[0]); ld8f(&Abf[a+1][8], &Xr[8]);
    } else {
#pragma unroll
      for (int i = 0; i < 16; ++i) Xr[i] = 0.f;
    }

    float res[16];
    float prev = 0.f;
#pragma unroll
    for (int k = 0; k < 32; ++k) {
      float fc = Xc[k];
      float qv = qs1 * fc;
      if (k & 15)         qv = fmaf(qs0, Xc[k-1], qv);
      if ((k & 15) != 15) qv = fmaf(qs2, Xc[k+1], qv);
      float acc = fmaf(wq1a, qv, wcf * fc);
      float tm = (k < 16) ? Xl[k]     : Xc[k-16];
      float wm = (k < 16) ? wmx       : wmh;
      acc = fmaf(wm, tm, acc);
      float tp = (k < 16) ? Xc[k+16]  : Xr[k-16];
      float wp = (k < 16) ? wpl       : wpx;
      acc = fmaf(wp, tp, acc);
      if (k & 1) res[k>>1] = 0.5f * (prev + acc);
      else       prev = acc;
    }

    float* outC = out + ((size_t)(bb*256 + C))*256 + 128 + 32*qq + 16*uh;
#pragma unroll
    for (int m = 0; m < 4; ++m) {
      float4 o4;
      o4.x = res[4*m]; o4.y = res[4*m+1]; o4.z = res[4*m+2]; o4.w = res[4*m+3];
      *(float4*)(outC + 4*m) = o4;
    }
  }
}

extern "C" void kernel_launch(void* const* d_in, const int* in_sizes, int n_in,
                              void* d_out, int out_size, void* d_ws, size_t ws_size,
                              hipStream_t stream) {
  (void)in_sizes; (void)n_in; (void)out_size; (void)d_ws; (void)ws_size;
  const float* x    = (const float*)d_in[0];
  const float* g    = (const float*)d_in[1];
  const float* be   = (const float*)d_in[2];
  const float* mn   = (const float*)d_in[3];
  const float* vr   = (const float*)d_in[4];
  const float* wqkv = (const float*)d_in[5];
  const float* wqs  = (const float*)d_in[6];
  const float* wks  = (const float*)d_in[7];
  float* out = (float*)d_out;

  fused_kernel<<<dim3(512), dim3(512), 0, stream>>>(x, g, be, mn, vr, wqkv, wqs, wks, out);
}

// Round 3
// 109.929 us; speedup vs baseline: 1.1735x; 1.0354x over previous
//
#include <hip/hip_runtime.h>

typedef __bf16 bf16;
typedef __attribute__((ext_vector_type(8))) __bf16 bf16x8;
typedef __attribute__((ext_vector_type(4))) __bf16 bf16x4;
typedef __attribute__((ext_vector_type(2))) __bf16 bf16x2;
typedef __attribute__((ext_vector_type(4))) float floatx4;

#define MFMA16(a,b,c) __builtin_amdgcn_mfma_f32_16x16x32_bf16((a),(b),(c),0,0,0)

__device__ __forceinline__ float fast_exp2(float xv) {
#if __has_builtin(__builtin_amdgcn_exp2f)
  return __builtin_amdgcn_exp2f(xv);
#else
  return exp2f(xv);
#endif
}

__device__ __forceinline__ void ld8f(const bf16* p, float* dst) {
  bf16x8 v = *(const bf16x8*)p;
#pragma unroll
  for (int i = 0; i < 8; ++i) dst[i] = (float)v[i];
}

// Fused attention (heads 0-3) + depthwise-conv residual (heads 4-7).
// grid = 512 (b=128 x slice h), block = 512 (8 waves; wave w owns i-rows 32w..32w+31).
// R3: full V^T (cv-folded) built ONCE -> main jt loop is barrier-free (3 barriers total,
// was 10). B-operand (i-row) LDS reads hoisted out of the jt loop. Epilogue rowsum
// broadcast via shuffles (no LDS).
// smem: Abf[256][72] bf16 @0 (36864) | VtF[64][264] bf16 @36864 (33792; scT/bsT union
//       during init) | ckA f32 @70656 | cvA f32 @71680 | total 72704 -> 2 blk/CU.
__global__ __launch_bounds__(512, 4) void fused_kernel(
    const float* __restrict__ x,
    const float* __restrict__ bn_gamma, const float* __restrict__ bn_beta,
    const float* __restrict__ bn_mean, const float* __restrict__ bn_var,
    const float* __restrict__ w_qkv, const float* __restrict__ w_qs,
    const float* __restrict__ w_ks,
    float* __restrict__ out)
{
  __shared__ __align__(16) char smem[72704];
  bf16 (*Abf)[72]  = (bf16(*)[72])smem;
  bf16 (*VtF)[264] = (bf16(*)[264])(smem + 36864);
  float* ckA = (float*)(smem + 70656);
  float* cvA = (float*)(smem + 71680);
  float* scT = (float*)(smem + 36864);          // init-phase union with VtF
  float* bsT = (float*)(smem + 36864 + 1024);

  const int t  = threadIdx.x;
  const int bb = blockIdx.x >> 2;
  const int h  = blockIdx.x & 3;

  if (t < 256) {
    float inv = rsqrtf(bn_var[t] + 1e-5f);
    float sc  = bn_gamma[t] * inv;
    scT[t] = sc;
    bsT[t] = bn_beta[t] - bn_mean[t] * sc;
    ckA[t] = w_qkv[t*6+2];
    cvA[t] = w_qkv[t*6+4];
  }
  __syncthreads();

  // stage A = relu(BN(x))[:, h*64 .. h*64+63] as bf16
  const float* xb = x + (size_t)bb * 65536 + h * 64;
  {
    const int rsub = t >> 4, ch = t & 15;
#pragma unroll
    for (int i2 = 0; i2 < 8; ++i2) {
      int n = i2*32 + rsub;
      float4 v = *(const float4*)(xb + (size_t)n*256 + ch*4);
      float sc = scT[n], bs = bsT[n];
      bf16x4 bv;
      bv.x = (bf16)fmaxf(fmaf(v.x, sc, bs), 0.f);
      bv.y = (bf16)fmaxf(fmaf(v.y, sc, bs), 0.f);
      bv.z = (bf16)fmaxf(fmaf(v.z, sc, bs), 0.f);
      bv.w = (bf16)fmaxf(fmaf(v.w, sc, bs), 0.f);
      *(bf16x4*)&Abf[n][ch*4] = bv;
    }
  }
  __syncthreads();   // Abf complete; scT/bsT dead -> VtF region reusable

  // build full V^T with cv folded: VtF[e][j] = cv[j] * A[j][e]
  {
    const int j32 = t & 31, g = t >> 5;   // g: 0..15 -> e rows 4g..4g+3
#pragma unroll
    for (int jt = 0; jt < 8; ++jt) {
      int j = jt*32 + j32;
      bf16x4 v = *(const bf16x4*)&Abf[j][g*4];
      float cv = cvA[j];
      VtF[g*4+0][j] = (bf16)((float)v.x * cv);
      VtF[g*4+1][j] = (bf16)((float)v.y * cv);
      VtF[g*4+2][j] = (bf16)((float)v.z * cv);
      VtF[g*4+3][j] = (bf16)((float)v.w * cv);
    }
  }
  __syncthreads();   // VtF + Abf stable for the rest of the kernel

  const int lane = t & 63;
  const int wid  = t >> 6;
  const int q    = lane >> 4;
  const int c    = lane & 15;
  const int R    = wid * 32;
  const bool hi  = (q >= 2);
  const int qa   = q & 1;
  const int srcA = ((qa*2)*16 + c) * 4;     // bpermute byte index, dwords 0,1
  const int srcB = ((qa*2+1)*16 + c) * 4;   // dwords 2,3

  float cqv[2];
  cqv[0] = w_qkv[(R + c)*6]      * 0.18033688f;  // SCALE * log2(e) folded
  cqv[1] = w_qkv[(R + 16 + c)*6] * 0.18033688f;

  // hoist jt-invariant B-operand (i-row) fragments
  bf16x8 bi0[2], bi1[2];
#pragma unroll
  for (int it = 0; it < 2; ++it) {
    const bf16* bp = &Abf[R + 16*it + c][0];
    bi0[it] = *(const bf16x8*)(bp + 8*q);
    bi1[it] = *(const bf16x8*)(bp + 32 + 8*q);
  }

  floatx4 oacc[2][4];
  float lacc[2] = {0.f, 0.f};
#pragma unroll
  for (int it = 0; it < 2; ++it)
#pragma unroll
    for (int et = 0; et < 4; ++et)
      oacc[it][et] = (floatx4){0.f,0.f,0.f,0.f};

  for (int jt = 0; jt < 8; ++jt) {
    const int j0 = jt * 32;

    // A-operand = j-rows (swapped-operand symmetric trick)
    bf16x8 aj00 = *(const bf16x8*)&Abf[j0 + c][8*q];
    bf16x8 aj01 = *(const bf16x8*)&Abf[j0 + c][32 + 8*q];
    bf16x8 aj10 = *(const bf16x8*)&Abf[j0 + 16 + c][8*q];
    bf16x8 aj11 = *(const bf16x8*)&Abf[j0 + 16 + c][32 + 8*q];
    floatx4 ckv0 = *(const floatx4*)&ckA[j0 + 4*q];
    floatx4 ckv1 = *(const floatx4*)&ckA[j0 + 16 + 4*q];

    unsigned int paU[2][4];
#pragma unroll
    for (int it = 0; it < 2; ++it) {
      floatx4 s0 = (floatx4){0.f,0.f,0.f,0.f};
      floatx4 s1 = (floatx4){0.f,0.f,0.f,0.f};
      s0 = MFMA16(aj00, bi0[it], s0); s0 = MFMA16(aj01, bi1[it], s0);
      s1 = MFMA16(aj10, bi0[it], s1); s1 = MFMA16(aj11, bi1[it], s1);
      // lane (q,c) holds G[j-local=4q+r][i=R+16it+c] = G[i][j] by symmetry
      float p0[4], p1[4];
#pragma unroll
      for (int r = 0; r < 4; ++r) {
        float e0v = fast_exp2(fminf(cqv[it]*ckv0[r]*s0[r], 80.f));
        float e1v = fast_exp2(fminf(cqv[it]*ckv1[r]*s1[r], 80.f));
        lacc[it] += e0v + e1v;
        p0[r] = e0v;
        p1[r] = e1v;
      }
      union { bf16x2 hh; unsigned int u; } pk00, pk01, pk10, pk11;
      pk00.hh = (bf16x2){(bf16)p0[0], (bf16)p0[1]};
      pk01.hh = (bf16x2){(bf16)p0[2], (bf16)p0[3]};
      pk10.hh = (bf16x2){(bf16)p1[0], (bf16)p1[1]};
      pk11.hh = (bf16x2){(bf16)p1[2], (bf16)p1[3]};
      // quad-regroup into A-operand layout for P*V
      unsigned int a0, a1;
      a0 = (unsigned)__builtin_amdgcn_ds_bpermute(srcA, (int)pk00.u);
      a1 = (unsigned)__builtin_amdgcn_ds_bpermute(srcA, (int)pk10.u);
      paU[it][0] = hi ? a1 : a0;
      a0 = (unsigned)__builtin_amdgcn_ds_bpermute(srcA, (int)pk01.u);
      a1 = (unsigned)__builtin_amdgcn_ds_bpermute(srcA, (int)pk11.u);
      paU[it][1] = hi ? a1 : a0;
      a0 = (unsigned)__builtin_amdgcn_ds_bpermute(srcB, (int)pk00.u);
      a1 = (unsigned)__builtin_amdgcn_ds_bpermute(srcB, (int)pk10.u);
      paU[it][2] = hi ? a1 : a0;
      a0 = (unsigned)__builtin_amdgcn_ds_bpermute(srcB, (int)pk01.u);
      a1 = (unsigned)__builtin_amdgcn_ds_bpermute(srcB, (int)pk11.u);
      paU[it][3] = hi ? a1 : a0;
    }

    union PAu { unsigned int u[4]; bf16x8 v; };
    PAu pa0, pa1;
#pragma unroll
    for (int k = 0; k < 4; ++k) { pa0.u[k] = paU[0][k]; pa1.u[k] = paU[1][k]; }

#pragma unroll
    for (int et = 0; et < 4; ++et) {
      bf16x8 vb = *(const bf16x8*)&VtF[16*et + c][j0 + 8*q];
      oacc[0][et] = MFMA16(pa0.v, vb, oacc[0][et]);
      oacc[1][et] = MFMA16(pa1.v, vb, oacc[1][et]);
    }
  }

  // rowsum reduce across quads; redistribute via shuffles (no LDS, no barrier)
#pragma unroll
  for (int it = 0; it < 2; ++it) {
    float v = lacc[it];
    v += __shfl_xor(v, 16, 64);
    v += __shfl_xor(v, 32, 64);
    lacc[it] = v;   // full rowsum for i = R+16it+c, duplicated across quads
  }

  float* outA = out + ((size_t)bb*256)*256 + h*32;
#pragma unroll
  for (int it = 0; it < 2; ++it) {
#pragma unroll
    for (int r = 0; r < 4; ++r) {
      float lsrc = __shfl(lacc[it], 4*q + r, 64);  // lane 4q+r holds l[R+16it+4q+r]
      float linv = 0.5f / lsrc;                    // fold pair-average 0.5
      int n = R + 16*it + 4*q + r;
#pragma unroll
      for (int et = 0; et < 4; ++et) {
        float v = oacc[it][et][r];
        float v2 = v + __shfl_xor(v, 1, 64);
        if (!(lane & 1))
          outA[(size_t)n*256 + 8*et + (c>>1)] = v2 * linv;
      }
    }
  }

  // ---------------- conv phase (heads 4..7), reads Abf ----------------
  // thread: C-row ci, quarter qq, half uh; p = 64*qq + 32*uh + k, k=0..31
  {
    const int ci = t >> 3, sub = t & 7, qq = sub >> 1, uh = sub & 1;
    const int C  = h*64 + ci;
    const int a  = 4*ci + qq;
    const int e0 = 32*uh;

    float qs0 = w_qs[C*3+0], qs1 = w_qs[C*3+1], qs2 = w_qs[C*3+2];
    float ks0 = w_ks[C*3+0], ks1 = w_ks[C*3+1], ks2 = w_ks[C*3+2];
    float wq1a = w_qkv[a*6+1], wk1a = w_qkv[a*6+3], wv1a = w_qkv[a*6+5];
    float wcf = fmaf(ks1, wk1a, wv1a);

    float wmx = 0.f;
    if (uh) wmx = ks0 * wk1a;
    else if (qq > 0) wmx = ks0 * w_qkv[(a-1)*6+3];
    float wmh = ks0 * wk1a;
    float wpl = ks2 * wk1a;
    float wpx = 0.f;
    if (!uh) wpx = ks2 * wk1a;
    else if (qq < 3) wpx = ks2 * w_qkv[(a+1)*6+3];

    float Xc[32], Xl[16], Xr[16];
#pragma unroll
    for (int m = 0; m < 4; ++m) ld8f(&Abf[a][e0 + 8*m], &Xc[8*m]);
    if (uh) {
      ld8f(&Abf[a][16], &Xl[0]); ld8f(&Abf[a][24], &Xl[8]);
    } else if (qq > 0) {
      ld8f(&Abf[a-1][48], &Xl[0]); ld8f(&Abf[a-1][56], &Xl[8]);
    } else {
#pragma unroll
      for (int i = 0; i < 16; ++i) Xl[i] = 0.f;
    }
    if (!uh) {
      ld8f(&Abf[a][32], &Xr[0]); ld8f(&Abf[a][40], &Xr[8]);
    } else if (qq < 3) {
      ld8f(&Abf[a+1][0], &Xr[0]); ld8f(&Abf[a+1][8], &Xr[8]);
    } else {
#pragma unroll
      for (int i = 0; i < 16; ++i) Xr[i] = 0.f;
    }

    float res[16];
    float prev = 0.f;
#pragma unroll
    for (int k = 0; k < 32; ++k) {
      float fc = Xc[k];
      float qv = qs1 * fc;
      if (k & 15)         qv = fmaf(qs0, Xc[k-1], qv);
      if ((k & 15) != 15) qv = fmaf(qs2, Xc[k+1], qv);
      float acc = fmaf(wq1a, qv, wcf * fc);
      float tm = (k < 16) ? Xl[k]     : Xc[k-16];
      float wm = (k < 16) ? wmx       : wmh;
      acc = fmaf(wm, tm, acc);
      float tp = (k < 16) ? Xc[k+16]  : Xr[k-16];
      float wp = (k < 16) ? wpl       : wpx;
      acc = fmaf(wp, tp, acc);
      if (k & 1) res[k>>1] = 0.5f * (prev + acc);
      else       prev = acc;
    }

    float* outC = out + ((size_t)(bb*256 + C))*256 + 128 + 32*qq + 16*uh;
#pragma unroll
    for (int m = 0; m < 4; ++m) {
      float4 o4;
      o4.x = res[4*m]; o4.y = res[4*m+1]; o4.z = res[4*m+2]; o4.w = res[4*m+3];
      *(float4*)(outC + 4*m) = o4;
    }
  }
}

extern "C" void kernel_launch(void* const* d_in, const int* in_sizes, int n_in,
                              void* d_out, int out_size, void* d_ws, size_t ws_size,
                              hipStream_t stream) {
  (void)in_sizes; (void)n_in; (void)out_size; (void)d_ws; (void)ws_size;
  const float* x    = (const float*)d_in[0];
  const float* g    = (const float*)d_in[1];
  const float* be   = (const float*)d_in[2];
  const float* mn   = (const float*)d_in[3];
  const float* vr   = (const float*)d_in[4];
  const float* wqkv = (const float*)d_in[5];
  const float* wqs  = (const float*)d_in[6];
  const float* wks  = (const float*)d_in[7];
  float* out = (float*)d_out;

  fused_kernel<<<dim3(512), dim3(512), 0, stream>>>(x, g, be, mn, vr, wqkv, wqs, wks, out);
}

// Round 4
// 107.084 us; speedup vs baseline: 1.2047x; 1.0266x over previous
//
#include <hip/hip_runtime.h>

typedef __bf16 bf16;
typedef __attribute__((ext_vector_type(8))) __bf16 bf16x8;
typedef __attribute__((ext_vector_type(4))) __bf16 bf16x4;
typedef __attribute__((ext_vector_type(4))) float floatx4;

#define MFMA16(a,b,c) __builtin_amdgcn_mfma_f32_16x16x32_bf16((a),(b),(c),0,0,0)

__device__ __forceinline__ float fast_exp2(float xv) {
#if __has_builtin(__builtin_amdgcn_exp2f)
  return __builtin_amdgcn_exp2f(xv);
#else
  return exp2f(xv);
#endif
}

__device__ __forceinline__ void ld8f(const bf16* p, float* dst) {
  bf16x8 v = *(const bf16x8*)p;
#pragma unroll
  for (int i = 0; i < 8; ++i) dst[i] = (float)v[i];
}

// Fused attention (heads 0-3) + depthwise-conv residual (heads 4-7).
// grid = 512 (b=128 x slice h), block = 512 (8 waves; wave w owns i-rows 32w..32w+31).
// R4: j-permuted S-tiles. Swapped-operand S-MFMA with A-op row m -> physical j-row
// jmap(m) = 8*(m>>2)+(m&3) (tile s0; +4 for s1). Then lane (q,c)'s C-frag holds
// P[j0+8q+r][i] for r=0..3 (s0) and P[j0+8q+4+r][i] (s1) == EXACTLY the PV A-operand
// fragment of the same lane (k = 8q+jj). All 128 ds_bpermute + 64 cndmask per wave
// from R3 are deleted; C->A transform is now pure pack.
// smem: Abf[256][72] bf16 @0 (36864) | VtF[64][264] bf16 @36864 (33792; scT/bsT union
//       during init) | ckA f32 @70656 | cvA f32 @71680 | total 72704 -> 2 blk/CU.
__global__ __launch_bounds__(512, 4) void fused_kernel(
    const float* __restrict__ x,
    const float* __restrict__ bn_gamma, const float* __restrict__ bn_beta,
    const float* __restrict__ bn_mean, const float* __restrict__ bn_var,
    const float* __restrict__ w_qkv, const float* __restrict__ w_qs,
    const float* __restrict__ w_ks,
    float* __restrict__ out)
{
  __shared__ __align__(16) char smem[72704];
  bf16 (*Abf)[72]  = (bf16(*)[72])smem;
  bf16 (*VtF)[264] = (bf16(*)[264])(smem + 36864);
  float* ckA = (float*)(smem + 70656);
  float* cvA = (float*)(smem + 71680);
  float* scT = (float*)(smem + 36864);          // init-phase union with VtF
  float* bsT = (float*)(smem + 36864 + 1024);

  const int t  = threadIdx.x;
  const int bb = blockIdx.x >> 2;
  const int h  = blockIdx.x & 3;

  if (t < 256) {
    float inv = rsqrtf(bn_var[t] + 1e-5f);
    float sc  = bn_gamma[t] * inv;
    scT[t] = sc;
    bsT[t] = bn_beta[t] - bn_mean[t] * sc;
    ckA[t] = w_qkv[t*6+2];
    cvA[t] = w_qkv[t*6+4];
  }
  __syncthreads();

  // stage A = relu(BN(x))[:, h*64 .. h*64+63] as bf16
  const float* xb = x + (size_t)bb * 65536 + h * 64;
  {
    const int rsub = t >> 4, ch = t & 15;
#pragma unroll
    for (int i2 = 0; i2 < 8; ++i2) {
      int n = i2*32 + rsub;
      float4 v = *(const float4*)(xb + (size_t)n*256 + ch*4);
      float sc = scT[n], bs = bsT[n];
      bf16x4 bv;
      bv.x = (bf16)fmaxf(fmaf(v.x, sc, bs), 0.f);
      bv.y = (bf16)fmaxf(fmaf(v.y, sc, bs), 0.f);
      bv.z = (bf16)fmaxf(fmaf(v.z, sc, bs), 0.f);
      bv.w = (bf16)fmaxf(fmaf(v.w, sc, bs), 0.f);
      *(bf16x4*)&Abf[n][ch*4] = bv;
    }
  }
  __syncthreads();   // Abf complete; scT/bsT dead -> VtF region reusable

  // build full V^T with cv folded: VtF[e][j] = cv[j] * A[j][e]
  {
    const int j32 = t & 31, g = t >> 5;   // g: 0..15 -> e rows 4g..4g+3
#pragma unroll
    for (int jt = 0; jt < 8; ++jt) {
      int j = jt*32 + j32;
      bf16x4 v = *(const bf16x4*)&Abf[j][g*4];
      float cv = cvA[j];
      VtF[g*4+0][j] = (bf16)((float)v.x * cv);
      VtF[g*4+1][j] = (bf16)((float)v.y * cv);
      VtF[g*4+2][j] = (bf16)((float)v.z * cv);
      VtF[g*4+3][j] = (bf16)((float)v.w * cv);
    }
  }
  __syncthreads();   // VtF + Abf stable for the rest of the kernel

  const int lane = t & 63;
  const int wid  = t >> 6;
  const int q    = lane >> 4;
  const int c    = lane & 15;
  const int R    = wid * 32;
  const int jp   = ((c >> 2) << 3) + (c & 3);   // permuted j-row offset for A-op

  float cqv[2];
  cqv[0] = w_qkv[(R + c)*6]      * 0.18033688f;  // SCALE * log2(e) folded
  cqv[1] = w_qkv[(R + 16 + c)*6] * 0.18033688f;

  // hoist jt-invariant B-operand (i-row) fragments
  bf16x8 bi0[2], bi1[2];
#pragma unroll
  for (int it = 0; it < 2; ++it) {
    const bf16* bp = &Abf[R + 16*it + c][0];
    bi0[it] = *(const bf16x8*)(bp + 8*q);
    bi1[it] = *(const bf16x8*)(bp + 32 + 8*q);
  }

  floatx4 oacc[2][4];
  float lacc[2] = {0.f, 0.f};
#pragma unroll
  for (int it = 0; it < 2; ++it)
#pragma unroll
    for (int et = 0; et < 4; ++et)
      oacc[it][et] = (floatx4){0.f,0.f,0.f,0.f};

  for (int jt = 0; jt < 8; ++jt) {
    const int j0 = jt * 32;
    const int jr = j0 + jp;

    // A-operand = permuted j-rows (swapped-operand symmetric trick)
    bf16x8 aj00 = *(const bf16x8*)&Abf[jr][8*q];
    bf16x8 aj01 = *(const bf16x8*)&Abf[jr][32 + 8*q];
    bf16x8 aj10 = *(const bf16x8*)&Abf[jr + 4][8*q];
    bf16x8 aj11 = *(const bf16x8*)&Abf[jr + 4][32 + 8*q];
    floatx4 ckv0 = *(const floatx4*)&ckA[j0 + 8*q];      // ck[j0+8q+r]
    floatx4 ckv1 = *(const floatx4*)&ckA[j0 + 8*q + 4];  // ck[j0+8q+4+r]

    bf16x8 pa[2];
#pragma unroll
    for (int it = 0; it < 2; ++it) {
      floatx4 s0 = (floatx4){0.f,0.f,0.f,0.f};
      floatx4 s1 = (floatx4){0.f,0.f,0.f,0.f};
      s0 = MFMA16(aj00, bi0[it], s0); s0 = MFMA16(aj01, bi1[it], s0);
      s1 = MFMA16(aj10, bi0[it], s1); s1 = MFMA16(aj11, bi1[it], s1);
      // lane (q,c) reg r: s0 = G[j0+8q+r][i=R+16it+c], s1 = G[j0+8q+4+r][i]
      bf16x8 pv;
      float ps = 0.f;
#pragma unroll
      for (int r = 0; r < 4; ++r) {
        float e0v = fast_exp2(fminf(cqv[it]*ckv0[r]*s0[r], 80.f));
        float e1v = fast_exp2(fminf(cqv[it]*ckv1[r]*s1[r], 80.f));
        ps += e0v + e1v;
        pv[r]     = (bf16)e0v;   // A-frag jj = r      (j = j0+8q+r)
        pv[4 + r] = (bf16)e1v;   // A-frag jj = 4+r    (j = j0+8q+4+r)
      }
      lacc[it] += ps;
      pa[it] = pv;
    }

#pragma unroll
    for (int et = 0; et < 4; ++et) {
      bf16x8 vb = *(const bf16x8*)&VtF[16*et + c][j0 + 8*q];
      oacc[0][et] = MFMA16(pa[0], vb, oacc[0][et]);
      oacc[1][et] = MFMA16(pa[1], vb, oacc[1][et]);
    }
  }

  // rowsum reduce across quads; redistribute via shuffles (no LDS, no barrier)
#pragma unroll
  for (int it = 0; it < 2; ++it) {
    float v = lacc[it];
    v += __shfl_xor(v, 16, 64);
    v += __shfl_xor(v, 32, 64);
    lacc[it] = v;   // full rowsum for i = R+16it+c, duplicated across quads
  }

  float* outA = out + ((size_t)bb*256)*256 + h*32;
#pragma unroll
  for (int it = 0; it < 2; ++it) {
#pragma unroll
    for (int r = 0; r < 4; ++r) {
      float lsrc = __shfl(lacc[it], 4*q + r, 64);  // lane 4q+r holds l[R+16it+4q+r]
      float linv = 0.5f / lsrc;                    // fold pair-average 0.5
      int n = R + 16*it + 4*q + r;
#pragma unroll
      for (int et = 0; et < 4; ++et) {
        float v = oacc[it][et][r];
        float v2 = v + __shfl_xor(v, 1, 64);
        if (!(lane & 1))
          outA[(size_t)n*256 + 8*et + (c>>1)] = v2 * linv;
      }
    }
  }

  // ---------------- conv phase (heads 4..7), reads Abf ----------------
  // thread: C-row ci, quarter qq, half uh; p = 64*qq + 32*uh + k, k=0..31
  {
    const int ci = t >> 3, sub = t & 7, qq = sub >> 1, uh = sub & 1;
    const int C  = h*64 + ci;
    const int a  = 4*ci + qq;
    const int e0 = 32*uh;

    float qs0 = w_qs[C*3+0], qs1 = w_qs[C*3+1], qs2 = w_qs[C*3+2];
    float ks0 = w_ks[C*3+0], ks1 = w_ks[C*3+1], ks2 = w_ks[C*3+2];
    float wq1a = w_qkv[a*6+1], wk1a = w_qkv[a*6+3], wv1a = w_qkv[a*6+5];
    float wcf = fmaf(ks1, wk1a, wv1a);

    float wmx = 0.f;
    if (uh) wmx = ks0 * wk1a;
    else if (qq > 0) wmx = ks0 * w_qkv[(a-1)*6+3];
    float wmh = ks0 * wk1a;
    float wpl = ks2 * wk1a;
    float wpx = 0.f;
    if (!uh) wpx = ks2 * wk1a;
    else if (qq < 3) wpx = ks2 * w_qkv[(a+1)*6+3];

    float Xc[32], Xl[16], Xr[16];
#pragma unroll
    for (int m = 0; m < 4; ++m) ld8f(&Abf[a][e0 + 8*m], &Xc[8*m]);
    if (uh) {
      ld8f(&Abf[a][16], &Xl[0]); ld8f(&Abf[a][24], &Xl[8]);
    } else if (qq > 0) {
      ld8f(&Abf[a-1][48], &Xl[0]); ld8f(&Abf[a-1][56], &Xl[8]);
    } else {
#pragma unroll
      for (int i = 0; i < 16; ++i) Xl[i] = 0.f;
    }
    if (!uh) {
      ld8f(&Abf[a][32], &Xr[0]); ld8f(&Abf[a][40], &Xr[8]);
    } else if (qq < 3) {
      ld8f(&Abf[a+1][0], &Xr[0]); ld8f(&Abf[a+1][8], &Xr[8]);
    } else {
#pragma unroll
      for (int i = 0; i < 16; ++i) Xr[i] = 0.f;
    }

    float res[16];
    float prev = 0.f;
#pragma unroll
    for (int k = 0; k < 32; ++k) {
      float fc = Xc[k];
      float qv = qs1 * fc;
      if (k & 15)         qv = fmaf(qs0, Xc[k-1], qv);
      if ((k & 15) != 15) qv = fmaf(qs2, Xc[k+1], qv);
      float acc = fmaf(wq1a, qv, wcf * fc);
      float tm = (k < 16) ? Xl[k]     : Xc[k-16];
      float wm = (k < 16) ? wmx       : wmh;
      acc = fmaf(wm, tm, acc);
      float tp = (k < 16) ? Xc[k+16]  : Xr[k-16];
      float wp = (k < 16) ? wpl       : wpx;
      acc = fmaf(wp, tp, acc);
      if (k & 1) res[k>>1] = 0.5f * (prev + acc);
      else       prev = acc;
    }

    float* outC = out + ((size_t)(bb*256 + C))*256 + 128 + 32*qq + 16*uh;
#pragma unroll
    for (int m = 0; m < 4; ++m) {
      float4 o4;
      o4.x = res[4*m]; o4.y = res[4*m+1]; o4.z = res[4*m+2]; o4.w = res[4*m+3];
      *(float4*)(outC + 4*m) = o4;
    }
  }
}

extern "C" void kernel_launch(void* const* d_in, const int* in_sizes, int n_in,
                              void* d_out, int out_size, void* d_ws, size_t ws_size,
                              hipStream_t stream) {
  (void)in_sizes; (void)n_in; (void)out_size; (void)d_ws; (void)ws_size;
  const float* x    = (const float*)d_in[0];
  const float* g    = (const float*)d_in[1];
  const float* be   = (const float*)d_in[2];
  const float* mn   = (const float*)d_in[3];
  const float* vr   = (const float*)d_in[4];
  const float* wqkv = (const float*)d_in[5];
  const float* wqs  = (const float*)d_in[6];
  const float* wks  = (const float*)d_in[7];
  float* out = (float*)d_out;

  fused_kernel<<<dim3(512), dim3(512), 0, stream>>>(x, g, be, mn, vr, wqkv, wqs, wks, out);
}

// Round 5
// 106.025 us; speedup vs baseline: 1.2167x; 1.0100x over previous
//
#include <hip/hip_runtime.h>

typedef __bf16 bf16;
typedef __attribute__((ext_vector_type(8))) __bf16 bf16x8;
typedef __attribute__((ext_vector_type(4))) __bf16 bf16x4;
typedef __attribute__((ext_vector_type(4))) float floatx4;

#define MFMA16(a,b,c) __builtin_amdgcn_mfma_f32_16x16x32_bf16((a),(b),(c),0,0,0)

__device__ __forceinline__ float fast_exp2(float xv) {
#if __has_builtin(__builtin_amdgcn_exp2f)
  return __builtin_amdgcn_exp2f(xv);
#else
  return exp2f(xv);
#endif
}

__device__ __forceinline__ void ld8f(const bf16* p, float* dst) {
  bf16x8 v = *(const bf16x8*)p;
#pragma unroll
  for (int i = 0; i < 8; ++i) dst[i] = (float)v[i];
}

// Fused attention (heads 0-3) + depthwise-conv residual (heads 4-7).
// grid = 512 (b=128 x slice h), block = 512 (8 waves; wave w owns i-rows 32w..32w+31).
// R5: software-pipelined jt loop. aj fragments + ck vectors for jt+1 prefetched into
// a register double-buffer while jt computes; vb (V^T) reads issued BEFORE the S chain
// so their LDS latency hides under S-MFMA+exp; full unroll -> cross-iteration
// scheduling freedom (loop is barrier-free since R3). j-permutation trick from R4
// retained (C-frag == PV A-frag, zero cross-lane movement).
// smem: Abf[256][72] bf16 @0 (36864) | VtF[64][264] bf16 @36864 (33792; scT/bsT union
//       during init) | ckA f32 @70656 | cvA f32 @71680 | total 72704 -> 2 blk/CU.
__global__ __launch_bounds__(512, 4) void fused_kernel(
    const float* __restrict__ x,
    const float* __restrict__ bn_gamma, const float* __restrict__ bn_beta,
    const float* __restrict__ bn_mean, const float* __restrict__ bn_var,
    const float* __restrict__ w_qkv, const float* __restrict__ w_qs,
    const float* __restrict__ w_ks,
    float* __restrict__ out)
{
  __shared__ __align__(16) char smem[72704];
  bf16 (*Abf)[72]  = (bf16(*)[72])smem;
  bf16 (*VtF)[264] = (bf16(*)[264])(smem + 36864);
  float* ckA = (float*)(smem + 70656);
  float* cvA = (float*)(smem + 71680);
  float* scT = (float*)(smem + 36864);          // init-phase union with VtF
  float* bsT = (float*)(smem + 36864 + 1024);

  const int t  = threadIdx.x;
  const int bb = blockIdx.x >> 2;
  const int h  = blockIdx.x & 3;

  if (t < 256) {
    float inv = rsqrtf(bn_var[t] + 1e-5f);
    float sc  = bn_gamma[t] * inv;
    scT[t] = sc;
    bsT[t] = bn_beta[t] - bn_mean[t] * sc;
    ckA[t] = w_qkv[t*6+2];
    cvA[t] = w_qkv[t*6+4];
  }
  __syncthreads();

  // stage A = relu(BN(x))[:, h*64 .. h*64+63] as bf16
  const float* xb = x + (size_t)bb * 65536 + h * 64;
  {
    const int rsub = t >> 4, ch = t & 15;
#pragma unroll
    for (int i2 = 0; i2 < 8; ++i2) {
      int n = i2*32 + rsub;
      float4 v = *(const float4*)(xb + (size_t)n*256 + ch*4);
      float sc = scT[n], bs = bsT[n];
      bf16x4 bv;
      bv.x = (bf16)fmaxf(fmaf(v.x, sc, bs), 0.f);
      bv.y = (bf16)fmaxf(fmaf(v.y, sc, bs), 0.f);
      bv.z = (bf16)fmaxf(fmaf(v.z, sc, bs), 0.f);
      bv.w = (bf16)fmaxf(fmaf(v.w, sc, bs), 0.f);
      *(bf16x4*)&Abf[n][ch*4] = bv;
    }
  }
  __syncthreads();   // Abf complete; scT/bsT dead -> VtF region reusable

  // build full V^T with cv folded: VtF[e][j] = cv[j] * A[j][e]
  {
    const int j32 = t & 31, g = t >> 5;   // g: 0..15 -> e rows 4g..4g+3
#pragma unroll
    for (int jt = 0; jt < 8; ++jt) {
      int j = jt*32 + j32;
      bf16x4 v = *(const bf16x4*)&Abf[j][g*4];
      float cv = cvA[j];
      VtF[g*4+0][j] = (bf16)((float)v.x * cv);
      VtF[g*4+1][j] = (bf16)((float)v.y * cv);
      VtF[g*4+2][j] = (bf16)((float)v.z * cv);
      VtF[g*4+3][j] = (bf16)((float)v.w * cv);
    }
  }
  __syncthreads();   // VtF + Abf stable for the rest of the kernel

  const int lane = t & 63;
  const int wid  = t >> 6;
  const int q    = lane >> 4;
  const int c    = lane & 15;
  const int R    = wid * 32;
  const int jp   = ((c >> 2) << 3) + (c & 3);   // permuted j-row offset for A-op

  float cqv[2];
  cqv[0] = w_qkv[(R + c)*6]      * 0.18033688f;  // SCALE * log2(e) folded
  cqv[1] = w_qkv[(R + 16 + c)*6] * 0.18033688f;

  // hoist jt-invariant B-operand (i-row) fragments
  bf16x8 bi0[2], bi1[2];
#pragma unroll
  for (int it = 0; it < 2; ++it) {
    const bf16* bp = &Abf[R + 16*it + c][0];
    bi0[it] = *(const bf16x8*)(bp + 8*q);
    bi1[it] = *(const bf16x8*)(bp + 32 + 8*q);
  }

  floatx4 oacc[2][4];
  float lacc[2] = {0.f, 0.f};
#pragma unroll
  for (int it = 0; it < 2; ++it)
#pragma unroll
    for (int et = 0; et < 4; ++et)
      oacc[it][et] = (floatx4){0.f,0.f,0.f,0.f};

  // ---- software-pipelined jt loop: aj/ck prefetched one stage ahead ----
  bf16x8 a00 = *(const bf16x8*)&Abf[jp][8*q];
  bf16x8 a01 = *(const bf16x8*)&Abf[jp][32 + 8*q];
  bf16x8 a10 = *(const bf16x8*)&Abf[jp + 4][8*q];
  bf16x8 a11 = *(const bf16x8*)&Abf[jp + 4][32 + 8*q];
  floatx4 ck0 = *(const floatx4*)&ckA[8*q];
  floatx4 ck1 = *(const floatx4*)&ckA[8*q + 4];

#pragma unroll
  for (int jt = 0; jt < 8; ++jt) {
    const int j0 = jt * 32;

    // issue this jt's V^T reads first: latency hides under S+exp below
    bf16x8 vb0 = *(const bf16x8*)&VtF[     c][j0 + 8*q];
    bf16x8 vb1 = *(const bf16x8*)&VtF[16 + c][j0 + 8*q];
    bf16x8 vb2 = *(const bf16x8*)&VtF[32 + c][j0 + 8*q];
    bf16x8 vb3 = *(const bf16x8*)&VtF[48 + c][j0 + 8*q];

    // prefetch next iteration's A-operand + ck into the other buffer
    bf16x8 n00, n01, n10, n11; floatx4 nk0, nk1;
    if (jt < 7) {
      const int jr = j0 + 32 + jp;
      n00 = *(const bf16x8*)&Abf[jr][8*q];
      n01 = *(const bf16x8*)&Abf[jr][32 + 8*q];
      n10 = *(const bf16x8*)&Abf[jr + 4][8*q];
      n11 = *(const bf16x8*)&Abf[jr + 4][32 + 8*q];
      nk0 = *(const floatx4*)&ckA[j0 + 32 + 8*q];
      nk1 = *(const floatx4*)&ckA[j0 + 32 + 8*q + 4];
    }

    bf16x8 pa[2];
#pragma unroll
    for (int it = 0; it < 2; ++it) {
      floatx4 s0 = (floatx4){0.f,0.f,0.f,0.f};
      floatx4 s1 = (floatx4){0.f,0.f,0.f,0.f};
      s0 = MFMA16(a00, bi0[it], s0); s0 = MFMA16(a01, bi1[it], s0);
      s1 = MFMA16(a10, bi0[it], s1); s1 = MFMA16(a11, bi1[it], s1);
      // lane (q,c) reg r: s0 = G[j0+8q+r][i=R+16it+c], s1 = G[j0+8q+4+r][i]
      bf16x8 pv;
      float ps = 0.f;
#pragma unroll
      for (int r = 0; r < 4; ++r) {
        float e0v = fast_exp2(fminf(cqv[it]*ck0[r]*s0[r], 80.f));
        float e1v = fast_exp2(fminf(cqv[it]*ck1[r]*s1[r], 80.f));
        ps += e0v + e1v;
        pv[r]     = (bf16)e0v;   // A-frag jj = r      (j = j0+8q+r)
        pv[4 + r] = (bf16)e1v;   // A-frag jj = 4+r    (j = j0+8q+4+r)
      }
      lacc[it] += ps;
      pa[it] = pv;
    }

    oacc[0][0] = MFMA16(pa[0], vb0, oacc[0][0]);
    oacc[1][0] = MFMA16(pa[1], vb0, oacc[1][0]);
    oacc[0][1] = MFMA16(pa[0], vb1, oacc[0][1]);
    oacc[1][1] = MFMA16(pa[1], vb1, oacc[1][1]);
    oacc[0][2] = MFMA16(pa[0], vb2, oacc[0][2]);
    oacc[1][2] = MFMA16(pa[1], vb2, oacc[1][2]);
    oacc[0][3] = MFMA16(pa[0], vb3, oacc[0][3]);
    oacc[1][3] = MFMA16(pa[1], vb3, oacc[1][3]);

    // rotate pipeline registers
    a00 = n00; a01 = n01; a10 = n10; a11 = n11;
    ck0 = nk0; ck1 = nk1;
  }

  // rowsum reduce across quads; redistribute via shuffles (no LDS, no barrier)
#pragma unroll
  for (int it = 0; it < 2; ++it) {
    float v = lacc[it];
    v += __shfl_xor(v, 16, 64);
    v += __shfl_xor(v, 32, 64);
    lacc[it] = v;   // full rowsum for i = R+16it+c, duplicated across quads
  }

  float* outA = out + ((size_t)bb*256)*256 + h*32;
#pragma unroll
  for (int it = 0; it < 2; ++it) {
#pragma unroll
    for (int r = 0; r < 4; ++r) {
      float lsrc = __shfl(lacc[it], 4*q + r, 64);  // lane 4q+r holds l[R+16it+4q+r]
      float linv = 0.5f / lsrc;                    // fold pair-average 0.5
      int n = R + 16*it + 4*q + r;
#pragma unroll
      for (int et = 0; et < 4; ++et) {
        float v = oacc[it][et][r];
        float v2 = v + __shfl_xor(v, 1, 64);
        if (!(lane & 1))
          outA[(size_t)n*256 + 8*et + (c>>1)] = v2 * linv;
      }
    }
  }

  // ---------------- conv phase (heads 4..7), reads Abf ----------------
  // thread: C-row ci, quarter qq, half uh; p = 64*qq + 32*uh + k, k=0..31
  {
    const int ci = t >> 3, sub = t & 7, qq = sub >> 1, uh = sub & 1;
    const int C  = h*64 + ci;
    const int a  = 4*ci + qq;
    const int e0 = 32*uh;

    float qs0 = w_qs[C*3+0], qs1 = w_qs[C*3+1], qs2 = w_qs[C*3+2];
    float ks0 = w_ks[C*3+0], ks1 = w_ks[C*3+1], ks2 = w_ks[C*3+2];
    float wq1a = w_qkv[a*6+1], wk1a = w_qkv[a*6+3], wv1a = w_qkv[a*6+5];
    float wcf = fmaf(ks1, wk1a, wv1a);

    float wmx = 0.f;
    if (uh) wmx = ks0 * wk1a;
    else if (qq > 0) wmx = ks0 * w_qkv[(a-1)*6+3];
    float wmh = ks0 * wk1a;
    float wpl = ks2 * wk1a;
    float wpx = 0.f;
    if (!uh) wpx = ks2 * wk1a;
    else if (qq < 3) wpx = ks2 * w_qkv[(a+1)*6+3];

    float Xc[32], Xl[16], Xr[16];
#pragma unroll
    for (int m = 0; m < 4; ++m) ld8f(&Abf[a][e0 + 8*m], &Xc[8*m]);
    if (uh) {
      ld8f(&Abf[a][16], &Xl[0]); ld8f(&Abf[a][24], &Xl[8]);
    } else if (qq > 0) {
      ld8f(&Abf[a-1][48], &Xl[0]); ld8f(&Abf[a-1][56], &Xl[8]);
    } else {
#pragma unroll
      for (int i = 0; i < 16; ++i) Xl[i] = 0.f;
    }
    if (!uh) {
      ld8f(&Abf[a][32], &Xr[0]); ld8f(&Abf[a][40], &Xr[8]);
    } else if (qq < 3) {
      ld8f(&Abf[a+1][0], &Xr[0]); ld8f(&Abf[a+1][8], &Xr[8]);
    } else {
#pragma unroll
      for (int i = 0; i < 16; ++i) Xr[i] = 0.f;
    }

    float res[16];
    float prev = 0.f;
#pragma unroll
    for (int k = 0; k < 32; ++k) {
      float fc = Xc[k];
      float qv = qs1 * fc;
      if (k & 15)         qv = fmaf(qs0, Xc[k-1], qv);
      if ((k & 15) != 15) qv = fmaf(qs2, Xc[k+1], qv);
      float acc = fmaf(wq1a, qv, wcf * fc);
      float tm = (k < 16) ? Xl[k]     : Xc[k-16];
      float wm = (k < 16) ? wmx       : wmh;
      acc = fmaf(wm, tm, acc);
      float tp = (k < 16) ? Xc[k+16]  : Xr[k-16];
      float wp = (k < 16) ? wpl       : wpx;
      acc = fmaf(wp, tp, acc);
      if (k & 1) res[k>>1] = 0.5f * (prev + acc);
      else       prev = acc;
    }

    float* outC = out + ((size_t)(bb*256 + C))*256 + 128 + 32*qq + 16*uh;
#pragma unroll
    for (int m = 0; m < 4; ++m) {
      float4 o4;
      o4.x = res[4*m]; o4.y = res[4*m+1]; o4.z = res[4*m+2]; o4.w = res[4*m+3];
      *(float4*)(outC + 4*m) = o4;
    }
  }
}

extern "C" void kernel_launch(void* const* d_in, const int* in_sizes, int n_in,
                              void* d_out, int out_size, void* d_ws, size_t ws_size,
                              hipStream_t stream) {
  (void)in_sizes; (void)n_in; (void)out_size; (void)d_ws; (void)ws_size;
  const float* x    = (const float*)d_in[0];
  const float* g    = (const float*)d_in[1];
  const float* be   = (const float*)d_in[2];
  const float* mn   = (const float*)d_in[3];
  const float* vr   = (const float*)d_in[4];
  const float* wqkv = (const float*)d_in[5];
  const float* wqs  = (const float*)d_in[6];
  const float* wks  = (const float*)d_in[7];
  float* out = (float*)d_out;

  fused_kernel<<<dim3(512), dim3(512), 0, stream>>>(x, g, be, mn, vr, wqkv, wqs, wks, out);
}

// Round 6
// 104.983 us; speedup vs baseline: 1.2288x; 1.0099x over previous
//
#include <hip/hip_runtime.h>

typedef __bf16 bf16;
typedef __attribute__((ext_vector_type(8))) __bf16 bf16x8;
typedef __attribute__((ext_vector_type(4))) __bf16 bf16x4;
typedef __attribute__((ext_vector_type(2))) __bf16 bf16x2;
typedef __attribute__((ext_vector_type(4))) float floatx4;

#define MFMA16(a,b,c) __builtin_amdgcn_mfma_f32_16x16x32_bf16((a),(b),(c),0,0,0)

__device__ __forceinline__ float fast_exp2(float xv) {
#if __has_builtin(__builtin_amdgcn_exp2f)
  return __builtin_amdgcn_exp2f(xv);
#else
  return exp2f(xv);
#endif
}

__device__ __forceinline__ void ld8f(const bf16* p, float* dst) {
  bf16x8 v = *(const bf16x8*)p;
#pragma unroll
  for (int i = 0; i < 8; ++i) dst[i] = (float)v[i];
}

// Fused attention (heads 0-3) + depthwise-conv residual (heads 4-7).
// grid = 512 (b=128 x slice h), block = 512 (8 waves; wave w owns i-rows 32w..32w+31).
// R6: (1) cq*SCALE*log2e folded into B-operand regs -> per-jt softmax = 16 mul + 16 exp
// (no clamp: |arg| <= ~9 worst case). (2) rowsum l_i via ones-MFMA, landing directly in
// the epilogue layout (reg r = l[R+16it+4q+r]). (3) wave-staggered jt ring (wave w starts
// at jt=wid) to desynchronize LDS/SFU/MFMA bursts across the 8 lockstep waves.
// (4) unroll 2, no register rotation, VtF built with b32 writes.
// smem: Abf[256][72] bf16 @0 (36864) | VtF[64][264] bf16 @36864 (33792; scT/bsT union
//       during init) | ckA f32 @70656 | cvA f32 @71680 | total 72704 -> 2 blk/CU.
__global__ __launch_bounds__(512, 4) void fused_kernel(
    const float* __restrict__ x,
    const float* __restrict__ bn_gamma, const float* __restrict__ bn_beta,
    const float* __restrict__ bn_mean, const float* __restrict__ bn_var,
    const float* __restrict__ w_qkv, const float* __restrict__ w_qs,
    const float* __restrict__ w_ks,
    float* __restrict__ out)
{
  __shared__ __align__(16) char smem[72704];
  bf16 (*Abf)[72]  = (bf16(*)[72])smem;
  bf16 (*VtF)[264] = (bf16(*)[264])(smem + 36864);
  float* ckA = (float*)(smem + 70656);
  float* cvA = (float*)(smem + 71680);
  float* scT = (float*)(smem + 36864);          // init-phase union with VtF
  float* bsT = (float*)(smem + 36864 + 1024);

  const int t  = threadIdx.x;
  const int bb = blockIdx.x >> 2;
  const int h  = blockIdx.x & 3;

  if (t < 256) {
    float inv = rsqrtf(bn_var[t] + 1e-5f);
    float sc  = bn_gamma[t] * inv;
    scT[t] = sc;
    bsT[t] = bn_beta[t] - bn_mean[t] * sc;
    ckA[t] = w_qkv[t*6+2];
    cvA[t] = w_qkv[t*6+4];
  }
  __syncthreads();

  // stage A = relu(BN(x))[:, h*64 .. h*64+63] as bf16
  const float* xb = x + (size_t)bb * 65536 + h * 64;
  {
    const int rsub = t >> 4, ch = t & 15;
#pragma unroll
    for (int i2 = 0; i2 < 8; ++i2) {
      int n = i2*32 + rsub;
      float4 v = *(const float4*)(xb + (size_t)n*256 + ch*4);
      float sc = scT[n], bs = bsT[n];
      bf16x4 bv;
      bv.x = (bf16)fmaxf(fmaf(v.x, sc, bs), 0.f);
      bv.y = (bf16)fmaxf(fmaf(v.y, sc, bs), 0.f);
      bv.z = (bf16)fmaxf(fmaf(v.z, sc, bs), 0.f);
      bv.w = (bf16)fmaxf(fmaf(v.w, sc, bs), 0.f);
      *(bf16x4*)&Abf[n][ch*4] = bv;
    }
  }
  __syncthreads();   // Abf complete; scT/bsT dead -> VtF region reusable

  // build full V^T with cv folded: VtF[e][j] = cv[j] * A[j][e]; b32 writes (j-pairs)
  {
    const int J  = t & 127;      // j-pair index: j = 2J, 2J+1
    const int eg = t >> 7;       // e-group: e in [16eg, 16eg+16)
    const bf16* r0 = &Abf[2*J][16*eg];
    const bf16* r1 = &Abf[2*J + 1][16*eg];
    bf16x8 a0l = *(const bf16x8*)r0, a0h = *(const bf16x8*)(r0 + 8);
    bf16x8 a1l = *(const bf16x8*)r1, a1h = *(const bf16x8*)(r1 + 8);
    float cv0 = cvA[2*J], cv1 = cvA[2*J + 1];
#pragma unroll
    for (int e = 0; e < 8; ++e) {
      union { bf16x2 hh; unsigned u; } wl, wh;
      wl.hh = (bf16x2){(bf16)((float)a0l[e]*cv0), (bf16)((float)a1l[e]*cv1)};
      wh.hh = (bf16x2){(bf16)((float)a0h[e]*cv0), (bf16)((float)a1h[e]*cv1)};
      *(unsigned*)&VtF[16*eg + e][2*J]     = wl.u;
      *(unsigned*)&VtF[16*eg + 8 + e][2*J] = wh.u;
    }
  }
  __syncthreads();   // VtF + Abf stable for the rest of the kernel

  const int lane = t & 63;
  const int wid  = t >> 6;
  const int q    = lane >> 4;
  const int c    = lane & 15;
  const int R    = wid * 32;
  const int jp   = ((c >> 2) << 3) + (c & 3);   // permuted j-row offset for A-op

  // B-operand (i-row) fragments, pre-scaled by cq_i * SCALE * log2(e)
  float cqs[2];
  cqs[0] = w_qkv[(R + c)*6]      * 0.18033688f;
  cqs[1] = w_qkv[(R + 16 + c)*6] * 0.18033688f;
  bf16x8 bi0[2], bi1[2];
#pragma unroll
  for (int it = 0; it < 2; ++it) {
    const bf16* bp = &Abf[R + 16*it + c][0];
    bf16x8 r0 = *(const bf16x8*)(bp + 8*q);
    bf16x8 r1 = *(const bf16x8*)(bp + 32 + 8*q);
#pragma unroll
    for (int e = 0; e < 8; ++e) {
      bi0[it][e] = (bf16)((float)r0[e] * cqs[it]);
      bi1[it][e] = (bf16)((float)r1[e] * cqs[it]);
    }
  }

  bf16x8 vbONE;
#pragma unroll
  for (int e = 0; e < 8; ++e) vbONE[e] = (bf16)1.0f;

  floatx4 oacc[2][4];
  floatx4 oaccL[2];
#pragma unroll
  for (int it = 0; it < 2; ++it) {
    oaccL[it] = (floatx4){0.f,0.f,0.f,0.f};
#pragma unroll
    for (int et = 0; et < 4; ++et)
      oacc[it][et] = (floatx4){0.f,0.f,0.f,0.f};
  }

  const int jbase = wid & 7;   // wave-staggered jt ring
#pragma unroll 2
  for (int jt = 0; jt < 8; ++jt) {
    const int j0 = (((jt + jbase) & 7) << 5);

    // issue this jt's V^T reads first: latency hides under S+exp below
    bf16x8 vb0 = *(const bf16x8*)&VtF[     c][j0 + 8*q];
    bf16x8 vb1 = *(const bf16x8*)&VtF[16 + c][j0 + 8*q];
    bf16x8 vb2 = *(const bf16x8*)&VtF[32 + c][j0 + 8*q];
    bf16x8 vb3 = *(const bf16x8*)&VtF[48 + c][j0 + 8*q];

    // A-operand = permuted j-rows (swapped-operand symmetric trick)
    const int jr = j0 + jp;
    bf16x8 aj00 = *(const bf16x8*)&Abf[jr][8*q];
    bf16x8 aj01 = *(const bf16x8*)&Abf[jr][32 + 8*q];
    bf16x8 aj10 = *(const bf16x8*)&Abf[jr + 4][8*q];
    bf16x8 aj11 = *(const bf16x8*)&Abf[jr + 4][32 + 8*q];
    floatx4 ck0 = *(const floatx4*)&ckA[j0 + 8*q];      // ck[j0+8q+r]
    floatx4 ck1 = *(const floatx4*)&ckA[j0 + 8*q + 4];  // ck[j0+8q+4+r]

    bf16x8 pa[2];
#pragma unroll
    for (int it = 0; it < 2; ++it) {
      floatx4 s0 = (floatx4){0.f,0.f,0.f,0.f};
      floatx4 s1 = (floatx4){0.f,0.f,0.f,0.f};
      s0 = MFMA16(aj00, bi0[it], s0); s0 = MFMA16(aj01, bi1[it], s0);
      s1 = MFMA16(aj10, bi0[it], s1); s1 = MFMA16(aj11, bi1[it], s1);
      // s pre-scaled by cq*SCALE*log2e; reg r: s0 -> j=j0+8q+r, s1 -> j=j0+8q+4+r
      bf16x8 pv;
#pragma unroll
      for (int r = 0; r < 4; ++r) {
        pv[r]     = (bf16)fast_exp2(ck0[r] * s0[r]);
        pv[4 + r] = (bf16)fast_exp2(ck1[r] * s1[r]);
      }
      pa[it] = pv;
    }

    // rowsum via ones-MFMA: lands as l[R+16it+4q+r] in reg r (all c equal)
    oaccL[0] = MFMA16(pa[0], vbONE, oaccL[0]);
    oaccL[1] = MFMA16(pa[1], vbONE, oaccL[1]);

    oacc[0][0] = MFMA16(pa[0], vb0, oacc[0][0]);
    oacc[1][0] = MFMA16(pa[1], vb0, oacc[1][0]);
    oacc[0][1] = MFMA16(pa[0], vb1, oacc[0][1]);
    oacc[1][1] = MFMA16(pa[1], vb1, oacc[1][1]);
    oacc[0][2] = MFMA16(pa[0], vb2, oacc[0][2]);
    oacc[1][2] = MFMA16(pa[1], vb2, oacc[1][2]);
    oacc[0][3] = MFMA16(pa[0], vb3, oacc[0][3]);
    oacc[1][3] = MFMA16(pa[1], vb3, oacc[1][3]);
  }

  float* outA = out + ((size_t)bb*256)*256 + h*32;
#pragma unroll
  for (int it = 0; it < 2; ++it) {
#pragma unroll
    for (int r = 0; r < 4; ++r) {
      float linv = 0.5f / oaccL[it][r];            // fold pair-average 0.5
      int n = R + 16*it + 4*q + r;
#pragma unroll
      for (int et = 0; et < 4; ++et) {
        float v = oacc[it][et][r];
        float v2 = v + __shfl_xor(v, 1, 64);
        if (!(lane & 1))
          outA[(size_t)n*256 + 8*et + (c>>1)] = v2 * linv;
      }
    }
  }

  // ---------------- conv phase (heads 4..7), reads Abf ----------------
  // thread: C-row ci, quarter qq, half uh; p = 64*qq + 32*uh + k, k=0..31
  {
    const int ci = t >> 3, sub = t & 7, qq = sub >> 1, uh = sub & 1;
    const int C  = h*64 + ci;
    const int a  = 4*ci + qq;
    const int e0 = 32*uh;

    float qs0 = w_qs[C*3+0], qs1 = w_qs[C*3+1], qs2 = w_qs[C*3+2];
    float ks0 = w_ks[C*3+0], ks1 = w_ks[C*3+1], ks2 = w_ks[C*3+2];
    float wq1a = w_qkv[a*6+1], wk1a = w_qkv[a*6+3], wv1a = w_qkv[a*6+5];
    float wcf = fmaf(ks1, wk1a, wv1a);

    float wmx = 0.f;
    if (uh) wmx = ks0 * wk1a;
    else if (qq > 0) wmx = ks0 * w_qkv[(a-1)*6+3];
    float wmh = ks0 * wk1a;
    float wpl = ks2 * wk1a;
    float wpx = 0.f;
    if (!uh) wpx = ks2 * wk1a;
    else if (qq < 3) wpx = ks2 * w_qkv[(a+1)*6+3];

    float Xc[32], Xl[16], Xr[16];
#pragma unroll
    for (int m = 0; m < 4; ++m) ld8f(&Abf[a][e0 + 8*m], &Xc[8*m]);
    if (uh) {
      ld8f(&Abf[a][16], &Xl[0]); ld8f(&Abf[a][24], &Xl[8]);
    } else if (qq > 0) {
      ld8f(&Abf[a-1][48], &Xl[0]); ld8f(&Abf[a-1][56], &Xl[8]);
    } else {
#pragma unroll
      for (int i = 0; i < 16; ++i) Xl[i] = 0.f;
    }
    if (!uh) {
      ld8f(&Abf[a][32], &Xr[0]); ld8f(&Abf[a][40], &Xr[8]);
    } else if (qq < 3) {
      ld8f(&Abf[a+1][0], &Xr[0]); ld8f(&Abf[a+1][8], &Xr[8]);
    } else {
#pragma unroll
      for (int i = 0; i < 16; ++i) Xr[i] = 0.f;
    }

    float res[16];
    float prev = 0.f;
#pragma unroll
    for (int k = 0; k < 32; ++k) {
      float fc = Xc[k];
      float qv = qs1 * fc;
      if (k & 15)         qv = fmaf(qs0, Xc[k-1], qv);
      if ((k & 15) != 15) qv = fmaf(qs2, Xc[k+1], qv);
      float acc = fmaf(wq1a, qv, wcf * fc);
      float tm = (k < 16) ? Xl[k]     : Xc[k-16];
      float wm = (k < 16) ? wmx       : wmh;
      acc = fmaf(wm, tm, acc);
      float tp = (k < 16) ? Xc[k+16]  : Xr[k-16];
      float wp = (k < 16) ? wpl       : wpx;
      acc = fmaf(wp, tp, acc);
      if (k & 1) res[k>>1] = 0.5f * (prev + acc);
      else       prev = acc;
    }

    float* outC = out + ((size_t)(bb*256 + C))*256 + 128 + 32*qq + 16*uh;
#pragma unroll
    for (int m = 0; m < 4; ++m) {
      float4 o4;
      o4.x = res[4*m]; o4.y = res[4*m+1]; o4.z = res[4*m+2]; o4.w = res[4*m+3];
      *(float4*)(outC + 4*m) = o4;
    }
  }
}

extern "C" void kernel_launch(void* const* d_in, const int* in_sizes, int n_in,
                              void* d_out, int out_size, void* d_ws, size_t ws_size,
                              hipStream_t stream) {
  (void)in_sizes; (void)n_in; (void)out_size; (void)d_ws; (void)ws_size;
  const float* x    = (const float*)d_in[0];
  const float* g    = (const float*)d_in[1];
  const float* be   = (const float*)d_in[2];
  const float* mn   = (const float*)d_in[3];
  const float* vr   = (const float*)d_in[4];
  const float* wqkv = (const float*)d_in[5];
  const float* wqs  = (const float*)d_in[6];
  const float* wks  = (const float*)d_in[7];
  float* out = (float*)d_out;

  fused_kernel<<<dim3(512), dim3(512), 0, stream>>>(x, g, be, mn, vr, wqkv, wqs, wks, out);
}